// Round 5
// baseline (129.203 us; speedup 1.0000x reference)
//
#include <hip/hip_runtime.h>

#define NPTS 65536
#define NB_SHIFT 16   // log2(NPTS)
#define HID 64

typedef float vfloat4 __attribute__((ext_vector_type(4)));
typedef int   vint4   __attribute__((ext_vector_type(4)));

// ---------------- pre-pass: pos (B,3,N) -> xyzt (B,N) float4 ----------------
// Writer is (a) swizzled to the SAME XCD->point mapping the main kernel uses
// (so any line still allocated dirty-in-L2 is dirty in the READER's L2), and
// (b) stored nontemporally so lines are pushed toward L3 as clean data, which
// every XCD can then replicate into its own L2 on read.
__global__ __launch_bounds__(256) void xyzt_kernel(const float* __restrict__ pos,
                                                   vfloat4* __restrict__ xyzt) {
    const int j = blockIdx.x;                        // 1024 blocks
    const int g = ((j & 7) * 128 + (j >> 3)) * 256 + threadIdx.x;
    const int b = g >> NB_SHIFT;
    const int n = g & (NPTS - 1);
    const float* p = pos + (size_t)b * 3 * NPTS;
    vfloat4 v;
    v.x = p[n];
    v.y = p[n + NPTS];
    v.z = p[n + 2 * NPTS];
    v.w = 0.f;
    __builtin_nontemporal_store(v, xyzt + ((size_t)b << NB_SHIFT) + n);
}

// ---------------- main kernel: 4 threads per point ----------------
template <int USE_T>
__global__ __launch_bounds__(256, 4) void point_embed_kernel(
    const float*   __restrict__ pos,
    const vfloat4* __restrict__ xyzt,
    const int*     __restrict__ idx,
    const float*   __restrict__ dist,
    const float*   __restrict__ W,
    const float*   __restrict__ bias,
    float*         __restrict__ out) {
    __shared__ float featS[10][64];   // SoA; phase-2 reads broadcast
    const int tid = threadIdx.x;
    const int sub = tid & 3;          // which 4-neighbor slice of the point
    const int pl  = tid >> 2;         // local point 0..63

    // XCD swizzle: XCD k gets a contiguous half-batch -> 1 MB gather window
    const int blk = ((int)blockIdx.x & 7) * 512 + ((int)blockIdx.x >> 3);
    const int g = blk * 64 + pl;      // global point id
    const int b = g >> NB_SHIFT;
    const int n = g & (NPTS - 1);

    // coalesced: consecutive lanes read consecutive int4 / float4
    vint4   iq = ((const vint4*)idx)[(size_t)g * 4 + sub];
    vfloat4 dq = ((const vfloat4*)dist)[(size_t)g * 4 + sub];

    float cx, cy, cz;
    float mxx, mxy, mxz, mnx, mny, mnz;

    if (USE_T) {
        const vfloat4* xb = xyzt + ((size_t)b << NB_SHIFT);
        // 4 independent gathers -> all in flight at low VGPR
        vfloat4 q0 = xb[(unsigned)iq.x];
        vfloat4 q1 = xb[(unsigned)iq.y];
        vfloat4 q2 = xb[(unsigned)iq.z];
        vfloat4 q3 = xb[(unsigned)iq.w];
        vfloat4 c  = xb[n];           // same addr across the 4 lanes of a point
        cx = c.x; cy = c.y; cz = c.z;
        mxx = fmaxf(fmaxf(q0.x, q1.x), fmaxf(q2.x, q3.x));
        mxy = fmaxf(fmaxf(q0.y, q1.y), fmaxf(q2.y, q3.y));
        mxz = fmaxf(fmaxf(q0.z, q1.z), fmaxf(q2.z, q3.z));
        mnx = fminf(fminf(q0.x, q1.x), fminf(q2.x, q3.x));
        mny = fminf(fminf(q0.y, q1.y), fminf(q2.y, q3.y));
        mnz = fminf(fminf(q0.z, q1.z), fminf(q2.z, q3.z));
    } else {
        const float* px = pos + (size_t)b * 3 * NPTS;
        cx = px[n]; cy = px[n + NPTS]; cz = px[n + 2 * NPTS];
        mxx = mxy = mxz = -INFINITY;
        mnx = mny = mnz = INFINITY;
        int ids[4] = {iq.x, iq.y, iq.z, iq.w};
#pragma unroll
        for (int j = 0; j < 4; ++j) {
            float qx = px[(unsigned)ids[j]];
            float qy = px[(unsigned)ids[j] + NPTS];
            float qz = px[(unsigned)ids[j] + 2 * NPTS];
            mxx = fmaxf(mxx, qx); mxy = fmaxf(mxy, qy); mxz = fmaxf(mxz, qz);
            mnx = fminf(mnx, qx); mny = fminf(mny, qy); mnz = fminf(mnz, qz);
        }
    }
    float md = fmaxf(fmaxf(dq.x, dq.y), fmaxf(dq.z, dq.w));

    // butterfly across the 4 lanes of each point (lanes ^1, ^2)
#pragma unroll
    for (int m = 1; m <= 2; m <<= 1) {
        mxx = fmaxf(mxx, __shfl_xor(mxx, m));
        mxy = fmaxf(mxy, __shfl_xor(mxy, m));
        mxz = fmaxf(mxz, __shfl_xor(mxz, m));
        mnx = fminf(mnx, __shfl_xor(mnx, m));
        mny = fminf(mny, __shfl_xor(mny, m));
        mnz = fminf(mnz, __shfl_xor(mnz, m));
        md  = fmaxf(md,  __shfl_xor(md,  m));
    }

    if (sub == 0) {   // 16 active lanes/wave, consecutive addrs: no conflict
        featS[0][pl] = cx;
        featS[1][pl] = cy;
        featS[2][pl] = cz;
        featS[3][pl] = mxx;
        featS[4][pl] = mxy;
        featS[5][pl] = mxz;
        featS[6][pl] = cx - mnx;
        featS[7][pl] = cy - mny;
        featS[8][pl] = cz - mnz;
        featS[9][pl] = md;
    }

    // W/bias: issued while waiting on the barrier; L2/L3-hot after block 0
    const int hq = tid & 15;
    vfloat4 Wv[10];
#pragma unroll
    for (int c = 0; c < 10; ++c)
        Wv[c] = ((const vfloat4*)(W + c * HID))[hq];
    vfloat4 bv = ((const vfloat4*)bias)[hq];

    __syncthreads();

    // --- phase 2: 64 points x 64 hidden, coalesced nontemporal stores ---
    const int prow = tid >> 4;                       // 0..15
    const size_t outbase = (size_t)blk * 64 * HID;
#pragma unroll
    for (int i = 0; i < 4; ++i) {
        const int p = i * 16 + prow;
        vfloat4 acc = bv;
#pragma unroll
        for (int c = 0; c < 10; ++c) {
            const float fv = featS[c][p];
            acc.x += fv * Wv[c].x;
            acc.y += fv * Wv[c].y;
            acc.z += fv * Wv[c].z;
            acc.w += fv * Wv[c].w;
        }
        acc.x = fmaxf(acc.x, 0.f);
        acc.y = fmaxf(acc.y, 0.f);
        acc.z = fmaxf(acc.z, 0.f);
        acc.w = fmaxf(acc.w, 0.f);
        __builtin_nontemporal_store(
            acc, (vfloat4*)(out + outbase + (size_t)p * HID) + hq);
    }
}

extern "C" void kernel_launch(void* const* d_in, const int* in_sizes, int n_in,
                              void* d_out, int out_size, void* d_ws, size_t ws_size,
                              hipStream_t stream) {
    const float* pos  = (const float*)d_in[0];
    const int*   idx  = (const int*)d_in[1];
    const float* dist = (const float*)d_in[2];
    const float* W    = (const float*)d_in[3];
    const float* bias = (const float*)d_in[4];
    float* out = (float*)d_out;

    const int total = in_sizes[0] / 3;       // B*N = 262144
    const size_t need = (size_t)total * sizeof(vfloat4);  // 16 MB

    if (ws_size >= need) {
        xyzt_kernel<<<total / 256, 256, 0, stream>>>(pos, (vfloat4*)d_ws);
        point_embed_kernel<1><<<total / 64, 256, 0, stream>>>(
            pos, (const vfloat4*)d_ws, idx, dist, W, bias, out);
    } else {
        point_embed_kernel<0><<<total / 64, 256, 0, stream>>>(
            pos, nullptr, idx, dist, W, bias, out);
    }
}

// Round 6
// 125.185 us; speedup vs baseline: 1.0321x; 1.0321x over previous
//
#include <hip/hip_runtime.h>
#include <hip/hip_fp16.h>

#define NPTS 65536
#define NB_SHIFT 16   // log2(NPTS)
#define HID 64

typedef float          vfloat4  __attribute__((ext_vector_type(4)));
typedef int            vint4    __attribute__((ext_vector_type(4)));
typedef unsigned short vushort4 __attribute__((ext_vector_type(4)));

// ---- pre-pass: pos (B,3,N) -> 8-byte fp16 table entries {x,y,z,pad} ----
// Writer block j covers the SAME point range as the main kernel's XCD-swizzled
// reader blocks with the same blockIdx%8, and stores CACHED (not nt): every
// table line ends up dirty in the reading XCD's own L2 -> minimum gather
// latency under the MSHR model.
__global__ __launch_bounds__(256) void xyzt_kernel(const float* __restrict__ pos,
                                                   vushort4* __restrict__ tab) {
    const int j = blockIdx.x;                        // 1024 blocks
    const int g = ((j & 7) * 128 + (j >> 3)) * 256 + threadIdx.x;
    const int b = g >> NB_SHIFT;
    const int n = g & (NPTS - 1);
    const float* p = pos + (size_t)b * 3 * NPTS;
    vushort4 v;
    v.x = __half_as_ushort(__float2half(p[n]));
    v.y = __half_as_ushort(__float2half(p[n + NPTS]));
    v.z = __half_as_ushort(__float2half(p[n + 2 * NPTS]));
    v.w = 0;
    tab[((size_t)b << NB_SHIFT) + n] = v;            // cached store
}

// ---------------- main kernel: 4 threads per point ----------------
template <int USE_T>
__global__ __launch_bounds__(256, 4) void point_embed_kernel(
    const float*    __restrict__ pos,
    const vushort4* __restrict__ tab,
    const int*      __restrict__ idx,
    const float*    __restrict__ dist,
    const float*    __restrict__ W,
    const float*    __restrict__ bias,
    float*          __restrict__ out) {
    __shared__ float featS[10][64];   // SoA; phase-2 reads broadcast
    const int tid = threadIdx.x;
    const int sub = tid & 3;          // which 4-neighbor slice of the point
    const int pl  = tid >> 2;         // local point 0..63

    // XCD swizzle: XCD k gathers only from its own 512 KiB table window
    const int blk = ((int)blockIdx.x & 7) * 512 + ((int)blockIdx.x >> 3);
    const int g = blk * 64 + pl;      // global point id
    const int b = g >> NB_SHIFT;
    const int n = g & (NPTS - 1);

    // coalesced: consecutive lanes read consecutive int4 / float4
    vint4   iq = ((const vint4*)idx)[(size_t)g * 4 + sub];
    vfloat4 dq = ((const vfloat4*)dist)[(size_t)g * 4 + sub];

    float cx = 0.f, cy = 0.f, cz = 0.f;
    float mxx, mxy, mxz, mnx, mny, mnz;
    const float* px = pos + (size_t)b * 3 * NPTS;

    if (USE_T) {
        const vushort4* xb = tab + ((size_t)b << NB_SHIFT);
        // 4 independent 8 B gathers, all in flight
        vushort4 u0 = xb[(unsigned)iq.x];
        vushort4 u1 = xb[(unsigned)iq.y];
        vushort4 u2 = xb[(unsigned)iq.z];
        vushort4 u3 = xb[(unsigned)iq.w];
        // center in fp32 (only the sub==0 lane consumes it)
        if (sub == 0) {
            cx = px[n]; cy = px[n + NPTS]; cz = px[n + 2 * NPTS];
        }
        float q0x = __half2float(__ushort_as_half(u0.x));
        float q0y = __half2float(__ushort_as_half(u0.y));
        float q0z = __half2float(__ushort_as_half(u0.z));
        float q1x = __half2float(__ushort_as_half(u1.x));
        float q1y = __half2float(__ushort_as_half(u1.y));
        float q1z = __half2float(__ushort_as_half(u1.z));
        float q2x = __half2float(__ushort_as_half(u2.x));
        float q2y = __half2float(__ushort_as_half(u2.y));
        float q2z = __half2float(__ushort_as_half(u2.z));
        float q3x = __half2float(__ushort_as_half(u3.x));
        float q3y = __half2float(__ushort_as_half(u3.y));
        float q3z = __half2float(__ushort_as_half(u3.z));
        mxx = fmaxf(fmaxf(q0x, q1x), fmaxf(q2x, q3x));
        mxy = fmaxf(fmaxf(q0y, q1y), fmaxf(q2y, q3y));
        mxz = fmaxf(fmaxf(q0z, q1z), fmaxf(q2z, q3z));
        mnx = fminf(fminf(q0x, q1x), fminf(q2x, q3x));
        mny = fminf(fminf(q0y, q1y), fminf(q2y, q3y));
        mnz = fminf(fminf(q0z, q1z), fminf(q2z, q3z));
    } else {
        cx = px[n]; cy = px[n + NPTS]; cz = px[n + 2 * NPTS];
        mxx = mxy = mxz = -INFINITY;
        mnx = mny = mnz = INFINITY;
        int ids[4] = {iq.x, iq.y, iq.z, iq.w};
#pragma unroll
        for (int j = 0; j < 4; ++j) {
            float qx = px[(unsigned)ids[j]];
            float qy = px[(unsigned)ids[j] + NPTS];
            float qz = px[(unsigned)ids[j] + 2 * NPTS];
            mxx = fmaxf(mxx, qx); mxy = fmaxf(mxy, qy); mxz = fmaxf(mxz, qz);
            mnx = fminf(mnx, qx); mny = fminf(mny, qy); mnz = fminf(mnz, qz);
        }
    }
    float md = fmaxf(fmaxf(dq.x, dq.y), fmaxf(dq.z, dq.w));

    // butterfly across the 4 lanes of each point (lanes ^1, ^2)
#pragma unroll
    for (int m = 1; m <= 2; m <<= 1) {
        mxx = fmaxf(mxx, __shfl_xor(mxx, m));
        mxy = fmaxf(mxy, __shfl_xor(mxy, m));
        mxz = fmaxf(mxz, __shfl_xor(mxz, m));
        mnx = fminf(mnx, __shfl_xor(mnx, m));
        mny = fminf(mny, __shfl_xor(mny, m));
        mnz = fminf(mnz, __shfl_xor(mnz, m));
        md  = fmaxf(md,  __shfl_xor(md,  m));
    }

    if (sub == 0) {   // 16 active lanes/wave, consecutive addrs: no conflict
        featS[0][pl] = cx;
        featS[1][pl] = cy;
        featS[2][pl] = cz;
        featS[3][pl] = mxx;
        featS[4][pl] = mxy;
        featS[5][pl] = mxz;
        featS[6][pl] = cx - mnx;
        featS[7][pl] = cy - mny;
        featS[8][pl] = cz - mnz;
        featS[9][pl] = md;
    }

    // W/bias: issued while waiting on the barrier; L2/L3-hot after block 0
    const int hq = tid & 15;
    vfloat4 Wv[10];
#pragma unroll
    for (int c = 0; c < 10; ++c)
        Wv[c] = ((const vfloat4*)(W + c * HID))[hq];
    vfloat4 bv = ((const vfloat4*)bias)[hq];

    __syncthreads();

    // --- phase 2: 64 points x 64 hidden, coalesced nontemporal stores ---
    const int prow = tid >> 4;                       // 0..15
    const size_t outbase = (size_t)blk * 64 * HID;
#pragma unroll
    for (int i = 0; i < 4; ++i) {
        const int p = i * 16 + prow;
        vfloat4 acc = bv;
#pragma unroll
        for (int c = 0; c < 10; ++c) {
            const float fv = featS[c][p];
            acc.x += fv * Wv[c].x;
            acc.y += fv * Wv[c].y;
            acc.z += fv * Wv[c].z;
            acc.w += fv * Wv[c].w;
        }
        acc.x = fmaxf(acc.x, 0.f);
        acc.y = fmaxf(acc.y, 0.f);
        acc.z = fmaxf(acc.z, 0.f);
        acc.w = fmaxf(acc.w, 0.f);
        __builtin_nontemporal_store(
            acc, (vfloat4*)(out + outbase + (size_t)p * HID) + hq);
    }
}

extern "C" void kernel_launch(void* const* d_in, const int* in_sizes, int n_in,
                              void* d_out, int out_size, void* d_ws, size_t ws_size,
                              hipStream_t stream) {
    const float* pos  = (const float*)d_in[0];
    const int*   idx  = (const int*)d_in[1];
    const float* dist = (const float*)d_in[2];
    const float* W    = (const float*)d_in[3];
    const float* bias = (const float*)d_in[4];
    float* out = (float*)d_out;

    const int total = in_sizes[0] / 3;       // B*N = 262144
    const size_t need = (size_t)total * sizeof(vushort4);  // 2 MB

    if (ws_size >= need) {
        xyzt_kernel<<<total / 256, 256, 0, stream>>>(pos, (vushort4*)d_ws);
        point_embed_kernel<1><<<total / 64, 256, 0, stream>>>(
            pos, (const vushort4*)d_ws, idx, dist, W, bias, out);
    } else {
        point_embed_kernel<0><<<total / 64, 256, 0, stream>>>(
            pos, nullptr, idx, dist, W, bias, out);
    }
}